// Round 3
// baseline (72.456 us; speedup 1.0000x reference)
//
#include <hip/hip_runtime.h>

// Problem constants (from reference):
#define BB 8
#define NN 32768
#define CC 4
#define MM 11          // memory length (FIR taps)
#define KK 55          // D*M
#define THREADS 256
#define SAMP 256                   // output samples per block (1 per thread, ALL 4 channels)
#define HALO (MM - 1)              // 10
#define SS (SAMP + HALO)           // 266 staged time samples

// out[b,c,n] = sum_{j=0..10} z[n-10+j] * ( sum_d W[c, d*11+j] * |z[n-10+j]|^d )
// z[t] = x[b,t,c,0] + i x[b,t,c,1], zero for t<0.
//
// Round-6 design: one thread = one sample x ALL FOUR channels.
//   - Weight indices are compile-time constants -> all 220 coefficient reads are
//     wave-uniform s_loads (scalar cache). No readfirstlane, no divergence.
//   - LDS per tap: 3 dense b128 reads (z pair0, z pair1, amp4) serve 4 channels
//     (round-5 spent 1 b128 + 1 b64 per 2 channels) -> ~40% fewer LDS instrs,
//     all canonical 16B-lane-stride conflict-free patterns.
//   - Per-thread fixed costs (staging loop, addressing, store setup) amortize
//     over 2x the outputs; total threads halve (1024 blocks x 256).
//   - Store: two adjacent float4s -> 32B/thread, full lines per wave pair of stores.
// Occupancy: 1024 blocks = 4 blocks/CU, 16 waves/CU; 8 independent accumulator
// chains/thread keep VALU latency hidden. LDS 12.8 KB/block.

__global__ __launch_bounds__(THREADS, 8)
void gmp_kernel(const float* __restrict__ x,
                const float* __restrict__ W,
                float* __restrict__ out) {
    __shared__ float4 z0s[SS];   // (re0, im0, re1, im1) at time t
    __shared__ float4 z1s[SS];   // (re2, im2, re3, im3) at time t
    __shared__ float4 ams[SS];   // (|z0|, |z1|, |z2|, |z3|) at time t

    const int tid = threadIdx.x;
    const int b  = blockIdx.y;
    const int n0 = blockIdx.x * SAMP;

    const float4* xg = (const float4*)x + (size_t)b * NN * 2;

    // Stage times n0-10 .. n0+255: two float4 loads per thread (32B, consecutive),
    // amplitudes computed once here and shared by the 11 consumers of each slot.
    for (int s = tid; s < SS; s += THREADS) {
        const int t = n0 - HALO + s;
        float4 v0 = make_float4(0.f, 0.f, 0.f, 0.f);
        float4 v1 = v0;
        if (t >= 0) { v0 = xg[2 * t]; v1 = xg[2 * t + 1]; }
        z0s[s] = v0;
        z1s[s] = v1;
        ams[s] = make_float4(sqrtf(fmaf(v0.x, v0.x, v0.y * v0.y)),
                             sqrtf(fmaf(v0.z, v0.z, v0.w * v0.w)),
                             sqrtf(fmaf(v1.x, v1.x, v1.y * v1.y)),
                             sqrtf(fmaf(v1.z, v1.z, v1.w * v1.w)));
    }
    __syncthreads();

    float ar0 = 0.f, ai0 = 0.f, ar1 = 0.f, ai1 = 0.f;
    float ar2 = 0.f, ai2 = 0.f, ar3 = 0.f, ai3 = 0.f;

    #pragma unroll
    for (int j = 0; j < MM; j++) {
        const float4 v0 = z0s[tid + j];
        const float4 v1 = z1s[tid + j];
        const float4 a  = ams[tid + j];
        // channel 0: weights row 0, amp a.x, z = (v0.x, v0.y)
        {
            float p = W[0 * KK + 4 * MM + j];
            p = fmaf(p, a.x, W[0 * KK + 3 * MM + j]);
            p = fmaf(p, a.x, W[0 * KK + 2 * MM + j]);
            p = fmaf(p, a.x, W[0 * KK + 1 * MM + j]);
            p = fmaf(p, a.x, W[0 * KK + 0 * MM + j]);
            ar0 = fmaf(v0.x, p, ar0);
            ai0 = fmaf(v0.y, p, ai0);
        }
        // channel 1: weights row 1, amp a.y, z = (v0.z, v0.w)
        {
            float p = W[1 * KK + 4 * MM + j];
            p = fmaf(p, a.y, W[1 * KK + 3 * MM + j]);
            p = fmaf(p, a.y, W[1 * KK + 2 * MM + j]);
            p = fmaf(p, a.y, W[1 * KK + 1 * MM + j]);
            p = fmaf(p, a.y, W[1 * KK + 0 * MM + j]);
            ar1 = fmaf(v0.z, p, ar1);
            ai1 = fmaf(v0.w, p, ai1);
        }
        // channel 2: weights row 2, amp a.z, z = (v1.x, v1.y)
        {
            float p = W[2 * KK + 4 * MM + j];
            p = fmaf(p, a.z, W[2 * KK + 3 * MM + j]);
            p = fmaf(p, a.z, W[2 * KK + 2 * MM + j]);
            p = fmaf(p, a.z, W[2 * KK + 1 * MM + j]);
            p = fmaf(p, a.z, W[2 * KK + 0 * MM + j]);
            ar2 = fmaf(v1.x, p, ar2);
            ai2 = fmaf(v1.y, p, ai2);
        }
        // channel 3: weights row 3, amp a.w, z = (v1.z, v1.w)
        {
            float p = W[3 * KK + 4 * MM + j];
            p = fmaf(p, a.w, W[3 * KK + 3 * MM + j]);
            p = fmaf(p, a.w, W[3 * KK + 2 * MM + j]);
            p = fmaf(p, a.w, W[3 * KK + 1 * MM + j]);
            p = fmaf(p, a.w, W[3 * KK + 0 * MM + j]);
            ar3 = fmaf(v1.z, p, ar3);
            ai3 = fmaf(v1.w, p, ai3);
        }
    }

    // out[b, n, 0..3, {re,im}] = 32 contiguous bytes per thread.
    const int n = n0 + tid;
    float4* og = (float4*)out + (size_t)(b * NN + n) * 2;
    og[0] = make_float4(ar0, ai0, ar1, ai1);
    og[1] = make_float4(ar2, ai2, ar3, ai3);
}

extern "C" void kernel_launch(void* const* d_in, const int* in_sizes, int n_in,
                              void* d_out, int out_size, void* d_ws, size_t ws_size,
                              hipStream_t stream) {
    const float* x = (const float*)d_in[0];   // [B,N,C,2] fp32
    const float* W = (const float*)d_in[1];   // [C,K] fp32
    float* out = (float*)d_out;               // [B,N,C,2] fp32

    dim3 grid(NN / SAMP, BB, 1);              // 128 x 8 = 1024 blocks
    gmp_kernel<<<grid, THREADS, 0, stream>>>(x, W, out);
}

// Round 4
// 63.200 us; speedup vs baseline: 1.1465x; 1.1465x over previous
//
#include <hip/hip_runtime.h>

// Problem constants (from reference):
#define BB 8
#define NN 32768
#define CC 4
#define MM 11          // memory length (FIR taps)
#define KK 55          // D*M
#define THREADS 256
#define SAMP 128                   // output samples per block (x both channel pairs)
#define HALO (MM - 1)              // 10
#define WSAMP 64                   // samples per wave
#define WSLOT (WSAMP + HALO)       // 74 staged slots per wave

// out[b,c,n] = sum_{j=0..10} z[n-10+j] * ( sum_d W[c, d*11+j] * |z[n-10+j]|^d )
// z[t] = x[b,t,c,0] + i x[b,t,c,1], zero for t<0.
//
// Round-7 design: WAVE-PRIVATE staging, ZERO barriers.
// Evidence so far: r0 (half-density global) == r2 (fully dense) at 32 waves/CU;
// r3 (16 waves/CU) = +8 us. => latency-bound / TLP-limited, access density
// irrelevant. The one untouched serial element is the block-wide __syncthreads
// gating every wave's compute on the SLOWEST of 4 waves' cold HBM staging loads
// (caches are freshly evicted by the harness's 268 MB poison fill).
// Here each wave stages its own 74 slots (64 samples + 10 halo, one channel
// pair) into private LDS and proceeds on its own lgkmcnt — 32 independent
// waves per CU, no rendezvous. All access patterns are ones already proven
// performance-neutral:
//   - staging loads / stores: 32B-stride half-density (== r0, tied r2)
//   - LDS reads: dense b128 (16B lane stride) + b64 — conflict-free
//   - weights: pair p = wave&1 via readfirstlane -> SGPR-uniform rows, s_load
// Residency: 2048 blocks x 4 waves = 32 waves/CU; VGPR <= 64 via launch_bounds.
// LDS: 4 waves x 74 x 24 B = 7.1 KB/block.

__global__ __launch_bounds__(THREADS, 8)
void gmp_kernel(const float* __restrict__ x,
                const float* __restrict__ W,
                float* __restrict__ out) {
    __shared__ float4 zs[4][WSLOT];    // [wave][slot]: (re_c, im_c, re_c+1, im_c+1)
    __shared__ float2 as2[4][WSLOT];   // [wave][slot]: |z| of the pair's channels

    const int tid = threadIdx.x;
    const int b  = blockIdx.y;
    const int n0 = blockIdx.x * SAMP;

    const int w = __builtin_amdgcn_readfirstlane(tid >> 6);  // wave id 0..3 (SGPR)
    const int l = tid & 63;                                  // lane
    const int p = w & 1;                                     // channel pair
    const int nw = n0 + ((w >> 1) << 6);                     // wave's first sample

    const float4* xg = (const float4*)x + (size_t)b * NN * 2;
    const int t0 = nw - HALO;                                // first staged time

    // Issue both staging loads up front (independent, overlap the cold miss).
    const int t1 = t0 + l;
    float4 v0 = make_float4(0.f, 0.f, 0.f, 0.f);
    if (t1 >= 0) v0 = xg[2 * t1 + p];
    float4 v1 = make_float4(0.f, 0.f, 0.f, 0.f);
    if (l < HALO) v1 = xg[2 * (t0 + 64 + l) + p];   // t0+64+l = nw+54+l >= 0 always

    zs[w][l] = v0;
    as2[w][l] = make_float2(sqrtf(fmaf(v0.x, v0.x, v0.y * v0.y)),
                            sqrtf(fmaf(v0.z, v0.z, v0.w * v0.w)));
    if (l < HALO) {
        zs[w][64 + l] = v1;
        as2[w][64 + l] = make_float2(sqrtf(fmaf(v1.x, v1.x, v1.y * v1.y)),
                                     sqrtf(fmaf(v1.z, v1.z, v1.w * v1.w)));
    }
    // No __syncthreads: each wave reads only its own region; the compiler's
    // lgkmcnt tracking orders same-wave LDS write->read.

    const float* W0 = W + (2 * p) * KK;        // SGPR-uniform -> s_load
    const float* W1 = W + (2 * p + 1) * KK;

    float ar0 = 0.f, ai0 = 0.f, ar1 = 0.f, ai1 = 0.f;

    #pragma unroll
    for (int j = 0; j < MM; j++) {
        const float4 v = zs[w][l + j];
        const float2 a = as2[w][l + j];
        // channel 2p
        {
            float pw = W0[4 * MM + j];
            pw = fmaf(pw, a.x, W0[3 * MM + j]);
            pw = fmaf(pw, a.x, W0[2 * MM + j]);
            pw = fmaf(pw, a.x, W0[1 * MM + j]);
            pw = fmaf(pw, a.x, W0[0 * MM + j]);
            ar0 = fmaf(v.x, pw, ar0);
            ai0 = fmaf(v.y, pw, ai0);
        }
        // channel 2p+1
        {
            float pw = W1[4 * MM + j];
            pw = fmaf(pw, a.y, W1[3 * MM + j]);
            pw = fmaf(pw, a.y, W1[2 * MM + j]);
            pw = fmaf(pw, a.y, W1[1 * MM + j]);
            pw = fmaf(pw, a.y, W1[0 * MM + j]);
            ar1 = fmaf(v.z, pw, ar1);
            ai1 = fmaf(v.w, pw, ai1);
        }
    }

    // out float4 index = (b*NN + nw + l)*2 + p; waves p=0/p=1 of the block
    // cover complementary 32B-stride halves of the same lines.
    const int n = nw + l;
    float4* og = (float4*)out + ((size_t)(b * NN + n) * 2 + p);
    *og = make_float4(ar0, ai0, ar1, ai1);
}

extern "C" void kernel_launch(void* const* d_in, const int* in_sizes, int n_in,
                              void* d_out, int out_size, void* d_ws, size_t ws_size,
                              hipStream_t stream) {
    const float* x = (const float*)d_in[0];   // [B,N,C,2] fp32
    const float* W = (const float*)d_in[1];   // [C,K] fp32
    float* out = (float*)d_out;               // [B,N,C,2] fp32

    dim3 grid(NN / SAMP, BB, 1);              // 256 x 8 = 2048 blocks
    gmp_kernel<<<grid, THREADS, 0, stream>>>(x, W, out);
}